// Round 1
// baseline (1499.930 us; speedup 1.0000x reference)
//
#include <hip/hip_runtime.h>
#include <hip/hip_bf16.h>

// ---------------------------------------------------------------------------
// GCN layer: out = relu(segment_sum(adj_vals * (x@W)[cols], rows))
//   x: [50000,256] f32, W: [256,128] f32, edges: 800000
// Stage 1: GEMM support = x @ W          (f32 vector ALU, LDS-tiled)
// Stage 2: scatter: out[rows[e]] += vals[e] * support[cols[e]]  (atomicAdd)
// Stage 3: relu in place
// ---------------------------------------------------------------------------

#define IN_F  256
#define OUT_F 128
#define GEMM_ROWS 32
#define GEMM_KC   32

__global__ __launch_bounds__(256) void gcn_gemm_kernel(
    const float* __restrict__ x, const float* __restrict__ w,
    float* __restrict__ support, int n_nodes)
{
    __shared__ float xs[GEMM_ROWS][GEMM_KC];   // 4 KB
    __shared__ float ws_[GEMM_KC][OUT_F];      // 16 KB

    const int row0 = blockIdx.x * GEMM_ROWS;
    const int col  = threadIdx.x & 127;        // 0..127
    const int rg   = threadIdx.x >> 7;         // 0 or 1 (row group of 16)

    float acc[16];
#pragma unroll
    for (int i = 0; i < 16; ++i) acc[i] = 0.f;

    for (int k0 = 0; k0 < IN_F; k0 += GEMM_KC) {
        // --- load x tile: 32 rows x 32 k = 1024 floats, 1 float4/thread ---
        {
            int r  = threadIdx.x >> 3;          // 0..31
            int kk = (threadIdx.x & 7) << 2;    // 0,4,..,28
            int row = row0 + r;
            float4 v;
            if (row < n_nodes) {
                v = *reinterpret_cast<const float4*>(&x[(size_t)row * IN_F + k0 + kk]);
            } else {
                v = make_float4(0.f, 0.f, 0.f, 0.f);
            }
            // flat index r*32+kk == threadIdx.x*4 -> contiguous ds_write_b128
            xs[r][kk]     = v.x;
            xs[r][kk + 1] = v.y;
            xs[r][kk + 2] = v.z;
            xs[r][kk + 3] = v.w;
        }
        // --- load w tile: 32 k x 128 cols = 4096 floats, 4 float4/thread ---
#pragma unroll
        for (int i = 0; i < 4; ++i) {
            int fi = threadIdx.x + i * 256;     // float4 index in [0,1024)
            int kk = fi >> 5;                   // 32 float4 per k-row
            int cc = (fi & 31) << 2;
            *reinterpret_cast<float4*>(&ws_[kk][cc]) =
                *reinterpret_cast<const float4*>(&w[(size_t)(k0 + kk) * OUT_F + cc]);
        }
        __syncthreads();

#pragma unroll
        for (int kk = 0; kk < GEMM_KC; ++kk) {
            float wv = ws_[kk][col];            // stride-1 across lanes: free
#pragma unroll
            for (int r = 0; r < 16; ++r)        // xs read is lane-broadcast
                acc[r] += xs[rg * 16 + r][kk] * wv;
        }
        __syncthreads();
    }

#pragma unroll
    for (int r = 0; r < 16; ++r) {
        int row = row0 + rg * 16 + r;
        if (row < n_nodes)
            support[(size_t)row * OUT_F + col] = acc[r];
    }
}

// one thread per (edge, 4-feature group): float4 gather + 4 atomic adds
__global__ __launch_bounds__(256) void gcn_scatter_kernel(
    const float* __restrict__ support, const float* __restrict__ vals,
    const int* __restrict__ rows, const int* __restrict__ cols,
    float* __restrict__ out, int n_edges)
{
    long long idx   = (long long)blockIdx.x * blockDim.x + threadIdx.x;
    long long total = (long long)n_edges * (OUT_F / 4);
    if (idx >= total) return;

    int e  = (int)(idx >> 5);       // /32 groups per edge
    int f4 = (int)(idx & 31);
    int r  = rows[e];
    int c  = cols[e];
    float v = vals[e];

    float4 s = *reinterpret_cast<const float4*>(&support[(size_t)c * OUT_F + f4 * 4]);
    float* o = &out[(size_t)r * OUT_F + f4 * 4];
    atomicAdd(o + 0, v * s.x);
    atomicAdd(o + 1, v * s.y);
    atomicAdd(o + 2, v * s.z);
    atomicAdd(o + 3, v * s.w);
}

__global__ __launch_bounds__(256) void gcn_relu_kernel(float* __restrict__ out, int n4)
{
    int idx = blockIdx.x * blockDim.x + threadIdx.x;
    if (idx >= n4) return;
    float4* p = reinterpret_cast<float4*>(out) + idx;
    float4 v = *p;
    v.x = fmaxf(v.x, 0.f);
    v.y = fmaxf(v.y, 0.f);
    v.z = fmaxf(v.z, 0.f);
    v.w = fmaxf(v.w, 0.f);
    *p = v;
}

extern "C" void kernel_launch(void* const* d_in, const int* in_sizes, int n_in,
                              void* d_out, int out_size, void* d_ws, size_t ws_size,
                              hipStream_t stream)
{
    const float* x    = (const float*)d_in[0];
    const float* w    = (const float*)d_in[1];
    const float* vals = (const float*)d_in[2];
    const int*   rows = (const int*)d_in[3];
    const int*   cols = (const int*)d_in[4];
    float* out = (float*)d_out;

    const int n_nodes = in_sizes[0] / IN_F;     // 50000
    const int n_edges = in_sizes[2];            // 800000

    float* support = (float*)d_ws;              // needs n_nodes*128*4 = 25.6 MB

    // zero the (poisoned) output for atomic accumulation
    hipMemsetAsync(d_out, 0, (size_t)out_size * sizeof(float), stream);

    // GEMM
    int gemm_blocks = (n_nodes + GEMM_ROWS - 1) / GEMM_ROWS;
    gcn_gemm_kernel<<<gemm_blocks, 256, 0, stream>>>(x, w, support, n_nodes);

    // scatter-add
    long long total = (long long)n_edges * (OUT_F / 4);
    int sc_blocks = (int)((total + 255) / 256);
    gcn_scatter_kernel<<<sc_blocks, 256, 0, stream>>>(support, vals, rows, cols, out, n_edges);

    // relu
    int n4 = out_size / 4;
    gcn_relu_kernel<<<(n4 + 255) / 256, 256, 0, stream>>>(out, n4);
}

// Round 2
// 387.720 us; speedup vs baseline: 3.8686x; 3.8686x over previous
//
#include <hip/hip_runtime.h>
#include <hip/hip_bf16.h>

// ---------------------------------------------------------------------------
// GCN layer: out = relu(segment_sum(adj_vals * (x@W)[cols], rows))
//   x: [50000,256] f32, W: [256,128] f32, edges: 800000
// Stage 1: GEMM support = x @ W                (f32 vector ALU, LDS-tiled)
// Stage 2: build CSR over destination rows     (int atomics only)
// Stage 3: per-node gather-accumulate + ReLU   (atomic-free, fused)
// Fallback (ws too small): old atomicAdd scatter path.
// ---------------------------------------------------------------------------

#define IN_F  256
#define OUT_F 128
#define GEMM_ROWS 32
#define GEMM_KC   32

// ---------------------------- Stage 1: GEMM -------------------------------
__global__ __launch_bounds__(256) void gcn_gemm_kernel(
    const float* __restrict__ x, const float* __restrict__ w,
    float* __restrict__ support, int n_nodes)
{
    __shared__ float xs[GEMM_ROWS][GEMM_KC];   // 4 KB
    __shared__ float ws_[GEMM_KC][OUT_F];      // 16 KB

    const int row0 = blockIdx.x * GEMM_ROWS;
    const int col  = threadIdx.x & 127;        // 0..127
    const int rg   = threadIdx.x >> 7;         // 0 or 1 (row group of 16)

    float acc[16];
#pragma unroll
    for (int i = 0; i < 16; ++i) acc[i] = 0.f;

    for (int k0 = 0; k0 < IN_F; k0 += GEMM_KC) {
        {
            int r  = threadIdx.x >> 3;          // 0..31
            int kk = (threadIdx.x & 7) << 2;    // 0,4,..,28
            int row = row0 + r;
            float4 v;
            if (row < n_nodes) {
                v = *reinterpret_cast<const float4*>(&x[(size_t)row * IN_F + k0 + kk]);
            } else {
                v = make_float4(0.f, 0.f, 0.f, 0.f);
            }
            xs[r][kk]     = v.x;
            xs[r][kk + 1] = v.y;
            xs[r][kk + 2] = v.z;
            xs[r][kk + 3] = v.w;
        }
#pragma unroll
        for (int i = 0; i < 4; ++i) {
            int fi = threadIdx.x + i * 256;
            int kk = fi >> 5;
            int cc = (fi & 31) << 2;
            *reinterpret_cast<float4*>(&ws_[kk][cc]) =
                *reinterpret_cast<const float4*>(&w[(size_t)(k0 + kk) * OUT_F + cc]);
        }
        __syncthreads();

#pragma unroll
        for (int kk = 0; kk < GEMM_KC; ++kk) {
            float wv = ws_[kk][col];
#pragma unroll
            for (int r = 0; r < 16; ++r)
                acc[r] += xs[rg * 16 + r][kk] * wv;
        }
        __syncthreads();
    }

#pragma unroll
    for (int r = 0; r < 16; ++r) {
        int row = row0 + rg * 16 + r;
        if (row < n_nodes)
            support[(size_t)row * OUT_F + col] = acc[r];
    }
}

// ------------------------- Stage 2: CSR build ------------------------------
__global__ __launch_bounds__(256) void gcn_hist_kernel(
    const int* __restrict__ rows, int* __restrict__ deg, int n_edges)
{
    int e = blockIdx.x * blockDim.x + threadIdx.x;
    if (e < n_edges) atomicAdd(&deg[rows[e]], 1);
}

// single-block exclusive scan over n (=50000) degrees
__global__ __launch_bounds__(256) void gcn_scan_kernel(
    const int* __restrict__ deg, int* __restrict__ offsets, int n)
{
    __shared__ int part[256];
    const int tid = threadIdx.x;
    const int chunk = (n + 255) / 256;
    const int start = tid * chunk;
    const int end   = min(start + chunk, n);

    int s = 0;
    for (int j = start; j < end; ++j) s += deg[j];
    part[tid] = s;
    __syncthreads();
    // Hillis-Steele inclusive scan
    for (int d = 1; d < 256; d <<= 1) {
        int t = (tid >= d) ? part[tid - d] : 0;
        __syncthreads();
        part[tid] += t;
        __syncthreads();
    }
    int run = part[tid] - s;   // exclusive prefix of this chunk
    for (int j = start; j < end; ++j) {
        offsets[j] = run;
        run += deg[j];
    }
    if (tid == 255) offsets[n] = run;
}

__global__ __launch_bounds__(256) void gcn_fill_kernel(
    const int* __restrict__ rows, const int* __restrict__ cols,
    const float* __restrict__ vals, const int* __restrict__ offsets,
    int* __restrict__ cnt, int* __restrict__ csr_col,
    float* __restrict__ csr_val, int n_edges)
{
    int e = blockIdx.x * blockDim.x + threadIdx.x;
    if (e >= n_edges) return;
    int r = rows[e];
    int pos = offsets[r] + atomicAdd(&cnt[r], 1);
    csr_col[pos] = cols[e];
    csr_val[pos] = vals[e];
}

// ---------------- Stage 3: per-node accumulate + ReLU ----------------------
// one wave per node; lane l owns features {2l, 2l+1}
__global__ __launch_bounds__(256) void gcn_gather_kernel(
    const float* __restrict__ support, const int* __restrict__ offsets,
    const int* __restrict__ deg, const int* __restrict__ csr_col,
    const float* __restrict__ csr_val, float* __restrict__ out, int n_nodes)
{
    const int node = blockIdx.x * 4 + (threadIdx.x >> 6);
    const int lane = threadIdx.x & 63;
    if (node >= n_nodes) return;

    const int off = offsets[node];
    const int d   = deg[node];

    float2 acc = make_float2(0.f, 0.f);
    int j = 0;
    // unroll by 2 for memory-level parallelism
    for (; j + 1 < d; j += 2) {
        int   c0 = csr_col[off + j];
        float v0 = csr_val[off + j];
        int   c1 = csr_col[off + j + 1];
        float v1 = csr_val[off + j + 1];
        float2 s0 = *reinterpret_cast<const float2*>(&support[(size_t)c0 * OUT_F + lane * 2]);
        float2 s1 = *reinterpret_cast<const float2*>(&support[(size_t)c1 * OUT_F + lane * 2]);
        acc.x += v0 * s0.x + v1 * s1.x;
        acc.y += v0 * s0.y + v1 * s1.y;
    }
    if (j < d) {
        int   c0 = csr_col[off + j];
        float v0 = csr_val[off + j];
        float2 s0 = *reinterpret_cast<const float2*>(&support[(size_t)c0 * OUT_F + lane * 2]);
        acc.x += v0 * s0.x;
        acc.y += v0 * s0.y;
    }

    float2 o;
    o.x = fmaxf(acc.x, 0.f);
    o.y = fmaxf(acc.y, 0.f);
    *reinterpret_cast<float2*>(&out[(size_t)node * OUT_F + lane * 2]) = o;
}

// ------------------------- Fallback (atomic) -------------------------------
__global__ __launch_bounds__(256) void gcn_scatter_kernel(
    const float* __restrict__ support, const float* __restrict__ vals,
    const int* __restrict__ rows, const int* __restrict__ cols,
    float* __restrict__ out, int n_edges)
{
    long long idx   = (long long)blockIdx.x * blockDim.x + threadIdx.x;
    long long total = (long long)n_edges * (OUT_F / 4);
    if (idx >= total) return;

    int e  = (int)(idx >> 5);
    int f4 = (int)(idx & 31);
    int r  = rows[e];
    int c  = cols[e];
    float v = vals[e];

    float4 s = *reinterpret_cast<const float4*>(&support[(size_t)c * OUT_F + f4 * 4]);
    float* o = &out[(size_t)r * OUT_F + f4 * 4];
    atomicAdd(o + 0, v * s.x);
    atomicAdd(o + 1, v * s.y);
    atomicAdd(o + 2, v * s.z);
    atomicAdd(o + 3, v * s.w);
}

__global__ __launch_bounds__(256) void gcn_relu_kernel(float* __restrict__ out, int n4)
{
    int idx = blockIdx.x * blockDim.x + threadIdx.x;
    if (idx >= n4) return;
    float4* p = reinterpret_cast<float4*>(out) + idx;
    float4 v = *p;
    v.x = fmaxf(v.x, 0.f);
    v.y = fmaxf(v.y, 0.f);
    v.z = fmaxf(v.z, 0.f);
    v.w = fmaxf(v.w, 0.f);
    *p = v;
}

// ---------------------------------------------------------------------------
extern "C" void kernel_launch(void* const* d_in, const int* in_sizes, int n_in,
                              void* d_out, int out_size, void* d_ws, size_t ws_size,
                              hipStream_t stream)
{
    const float* x    = (const float*)d_in[0];
    const float* w    = (const float*)d_in[1];
    const float* vals = (const float*)d_in[2];
    const int*   rows = (const int*)d_in[3];
    const int*   cols = (const int*)d_in[4];
    float* out = (float*)d_out;

    const int n_nodes = in_sizes[0] / IN_F;     // 50000
    const int n_edges = in_sizes[2];            // 800000

    // workspace layout
    char* p = (char*)d_ws;
    float* support = (float*)p;  p += (size_t)n_nodes * OUT_F * sizeof(float);
    int*   offsets = (int*)p;    p += (size_t)(n_nodes + 1) * sizeof(int);
    int*   deg     = (int*)p;    p += (size_t)n_nodes * sizeof(int);
    int*   cnt     = (int*)p;    p += (size_t)n_nodes * sizeof(int);
    int*   csr_col = (int*)p;    p += (size_t)n_edges * sizeof(int);
    float* csr_val = (float*)p;  p += (size_t)n_edges * sizeof(float);
    size_t needed = (size_t)(p - (char*)d_ws);

    // Stage 1: GEMM (both paths need it)
    int gemm_blocks = (n_nodes + GEMM_ROWS - 1) / GEMM_ROWS;
    gcn_gemm_kernel<<<gemm_blocks, 256, 0, stream>>>(x, w, support, n_nodes);

    const int eb = (n_edges + 255) / 256;

    if (ws_size >= needed) {
        // Stage 2: CSR build
        hipMemsetAsync(deg, 0, (size_t)n_nodes * sizeof(int), stream);
        hipMemsetAsync(cnt, 0, (size_t)n_nodes * sizeof(int), stream);
        gcn_hist_kernel<<<eb, 256, 0, stream>>>(rows, deg, n_edges);
        gcn_scan_kernel<<<1, 256, 0, stream>>>(deg, offsets, n_nodes);
        gcn_fill_kernel<<<eb, 256, 0, stream>>>(rows, cols, vals, offsets, cnt,
                                                csr_col, csr_val, n_edges);
        // Stage 3: atomic-free accumulate + fused ReLU (overwrites all of out)
        int gb = (n_nodes + 3) / 4;
        gcn_gather_kernel<<<gb, 256, 0, stream>>>(support, offsets, deg,
                                                  csr_col, csr_val, out, n_nodes);
    } else {
        // fallback: proven atomic path
        hipMemsetAsync(d_out, 0, (size_t)out_size * sizeof(float), stream);
        long long total = (long long)n_edges * (OUT_F / 4);
        int sc_blocks = (int)((total + 255) / 256);
        gcn_scatter_kernel<<<sc_blocks, 256, 0, stream>>>(support, vals, rows, cols,
                                                          out, n_edges);
        int n4 = out_size / 4;
        gcn_relu_kernel<<<(n4 + 255) / 256, 256, 0, stream>>>(out, n4);
    }
}

// Round 3
// 290.611 us; speedup vs baseline: 5.1613x; 1.3342x over previous
//
#include <hip/hip_runtime.h>
#include <hip/hip_bf16.h>

// ---------------------------------------------------------------------------
// GCN layer: out = relu(segment_sum(adj_vals * (x@W)[cols], rows))
//   x: [50000,256] f32, W: [256,128] f32, edges: 800000
// Stage 1: register-tiled GEMM support = x @ W  (f32, 64x128 tile, 4x8/thread)
// Stage 2: build CSR over destination rows      (int atomics only)
// Stage 3: per-node gather-accumulate + ReLU    (atomic-free, fused)
// Fallback (ws too small): atomicAdd scatter path.
// ---------------------------------------------------------------------------

#define IN_F  256
#define OUT_F 128

#define BM 64
#define BN 128
#define BK 32
#define XPAD 68   // padded LDS row for xs_t: keeps float4 alignment, spreads banks

// ---------------------------- Stage 1: GEMM -------------------------------
__global__ __launch_bounds__(256) void gcn_gemm_kernel(
    const float* __restrict__ x, const float* __restrict__ w,
    float* __restrict__ support, int n_nodes)
{
    __shared__ float xs_t[BK][XPAD];   // transposed x tile: [kk][row], ~8.7 KB
    __shared__ float ws_[BK][BN];      // w tile: 16 KB

    const int tid  = threadIdx.x;
    const int tx   = tid & 15;         // col group: 8 cols each
    const int ty   = tid >> 4;         // row group: 4 rows each
    const int row0 = blockIdx.x * BM;

    float acc[4][8];
#pragma unroll
    for (int i = 0; i < 4; ++i)
#pragma unroll
        for (int j = 0; j < 8; ++j) acc[i][j] = 0.f;

    for (int k0 = 0; k0 < IN_F; k0 += BK) {
        // load x tile 64 rows x 32 k (2 float4/thread), store transposed
#pragma unroll
        for (int i = 0; i < 2; ++i) {
            int t  = tid + i * 256;          // 0..511
            int r  = t >> 3;                 // 0..63
            int kk = (t & 7) << 2;           // 0,4,..,28
            int row = row0 + r;
            float4 v = make_float4(0.f, 0.f, 0.f, 0.f);
            if (row < n_nodes)
                v = *reinterpret_cast<const float4*>(&x[(size_t)row * IN_F + k0 + kk]);
            xs_t[kk + 0][r] = v.x;
            xs_t[kk + 1][r] = v.y;
            xs_t[kk + 2][r] = v.z;
            xs_t[kk + 3][r] = v.w;
        }
        // load w tile 32 k x 128 cols (4 float4/thread)
#pragma unroll
        for (int i = 0; i < 4; ++i) {
            int fi = tid + i * 256;          // float4 index 0..1023
            int kk = fi >> 5;
            int cc = (fi & 31) << 2;
            *reinterpret_cast<float4*>(&ws_[kk][cc]) =
                *reinterpret_cast<const float4*>(&w[(size_t)(k0 + kk) * OUT_F + cc]);
        }
        __syncthreads();

#pragma unroll
        for (int kk = 0; kk < BK; ++kk) {
            float4 a  = *reinterpret_cast<const float4*>(&xs_t[kk][ty * 4]);
            float4 b0 = *reinterpret_cast<const float4*>(&ws_[kk][tx * 8]);
            float4 b1 = *reinterpret_cast<const float4*>(&ws_[kk][tx * 8 + 4]);
            const float av[4] = {a.x, a.y, a.z, a.w};
            const float bv[8] = {b0.x, b0.y, b0.z, b0.w, b1.x, b1.y, b1.z, b1.w};
#pragma unroll
            for (int i = 0; i < 4; ++i)
#pragma unroll
                for (int j = 0; j < 8; ++j)
                    acc[i][j] += av[i] * bv[j];
        }
        __syncthreads();
    }

#pragma unroll
    for (int i = 0; i < 4; ++i) {
        int row = row0 + ty * 4 + i;
        if (row < n_nodes) {
            float4 o0 = make_float4(acc[i][0], acc[i][1], acc[i][2], acc[i][3]);
            float4 o1 = make_float4(acc[i][4], acc[i][5], acc[i][6], acc[i][7]);
            *reinterpret_cast<float4*>(&support[(size_t)row * OUT_F + tx * 8])     = o0;
            *reinterpret_cast<float4*>(&support[(size_t)row * OUT_F + tx * 8 + 4]) = o1;
        }
    }
}

// ------------------------- Stage 2: CSR build ------------------------------
__global__ __launch_bounds__(256) void gcn_hist_kernel(
    const int* __restrict__ rows, int* __restrict__ deg, int n_edges)
{
    int e = blockIdx.x * blockDim.x + threadIdx.x;
    if (e < n_edges) atomicAdd(&deg[rows[e]], 1);
}

// single-block exclusive scan over n (=50000) degrees, 1024 threads
__global__ __launch_bounds__(1024) void gcn_scan_kernel(
    const int* __restrict__ deg, int* __restrict__ offsets, int n)
{
    __shared__ int part[1024];
    const int tid   = threadIdx.x;
    const int chunk = (n + 1023) / 1024;
    const int start = tid * chunk;
    const int end   = min(start + chunk, n);

    int s = 0;
    for (int j = start; j < end; ++j) s += deg[j];
    part[tid] = s;
    __syncthreads();
    for (int d = 1; d < 1024; d <<= 1) {
        int t = (tid >= d) ? part[tid - d] : 0;
        __syncthreads();
        part[tid] += t;
        __syncthreads();
    }
    int run = part[tid] - s;   // exclusive prefix of this chunk
    for (int j = start; j < end; ++j) {
        offsets[j] = run;
        run += deg[j];
    }
    if (tid == 1023) offsets[n] = run;
}

__global__ __launch_bounds__(256) void gcn_fill_kernel(
    const int* __restrict__ rows, const int* __restrict__ cols,
    const float* __restrict__ vals, const int* __restrict__ offsets,
    int* __restrict__ cnt, int* __restrict__ csr_col,
    float* __restrict__ csr_val, int n_edges)
{
    int e = blockIdx.x * blockDim.x + threadIdx.x;
    if (e >= n_edges) return;
    int r = rows[e];
    int pos = offsets[r] + atomicAdd(&cnt[r], 1);
    csr_col[pos] = cols[e];
    csr_val[pos] = vals[e];
}

// ---------------- Stage 3: per-node accumulate + ReLU ----------------------
// one wave per node; lane l owns features {2l, 2l+1}
__global__ __launch_bounds__(256) void gcn_gather_kernel(
    const float* __restrict__ support, const int* __restrict__ offsets,
    const int* __restrict__ deg, const int* __restrict__ csr_col,
    const float* __restrict__ csr_val, float* __restrict__ out, int n_nodes)
{
    const int node = blockIdx.x * 4 + (threadIdx.x >> 6);
    const int lane = threadIdx.x & 63;
    if (node >= n_nodes) return;

    const int off = offsets[node];
    const int d   = deg[node];

    float2 acc = make_float2(0.f, 0.f);
    int j = 0;
    for (; j + 3 < d; j += 4) {
        int   c0 = csr_col[off + j];
        int   c1 = csr_col[off + j + 1];
        int   c2 = csr_col[off + j + 2];
        int   c3 = csr_col[off + j + 3];
        float v0 = csr_val[off + j];
        float v1 = csr_val[off + j + 1];
        float v2 = csr_val[off + j + 2];
        float v3 = csr_val[off + j + 3];
        float2 s0 = *reinterpret_cast<const float2*>(&support[(size_t)c0 * OUT_F + lane * 2]);
        float2 s1 = *reinterpret_cast<const float2*>(&support[(size_t)c1 * OUT_F + lane * 2]);
        float2 s2 = *reinterpret_cast<const float2*>(&support[(size_t)c2 * OUT_F + lane * 2]);
        float2 s3 = *reinterpret_cast<const float2*>(&support[(size_t)c3 * OUT_F + lane * 2]);
        acc.x += v0 * s0.x + v1 * s1.x + v2 * s2.x + v3 * s3.x;
        acc.y += v0 * s0.y + v1 * s1.y + v2 * s2.y + v3 * s3.y;
    }
    for (; j < d; ++j) {
        int   c0 = csr_col[off + j];
        float v0 = csr_val[off + j];
        float2 s0 = *reinterpret_cast<const float2*>(&support[(size_t)c0 * OUT_F + lane * 2]);
        acc.x += v0 * s0.x;
        acc.y += v0 * s0.y;
    }

    float2 o;
    o.x = fmaxf(acc.x, 0.f);
    o.y = fmaxf(acc.y, 0.f);
    *reinterpret_cast<float2*>(&out[(size_t)node * OUT_F + lane * 2]) = o;
}

// ------------------------- Fallback (atomic) -------------------------------
__global__ __launch_bounds__(256) void gcn_scatter_kernel(
    const float* __restrict__ support, const float* __restrict__ vals,
    const int* __restrict__ rows, const int* __restrict__ cols,
    float* __restrict__ out, int n_edges)
{
    long long idx   = (long long)blockIdx.x * blockDim.x + threadIdx.x;
    long long total = (long long)n_edges * (OUT_F / 4);
    if (idx >= total) return;

    int e  = (int)(idx >> 5);
    int f4 = (int)(idx & 31);
    int r  = rows[e];
    int c  = cols[e];
    float v = vals[e];

    float4 s = *reinterpret_cast<const float4*>(&support[(size_t)c * OUT_F + f4 * 4]);
    float* o = &out[(size_t)r * OUT_F + f4 * 4];
    atomicAdd(o + 0, v * s.x);
    atomicAdd(o + 1, v * s.y);
    atomicAdd(o + 2, v * s.z);
    atomicAdd(o + 3, v * s.w);
}

__global__ __launch_bounds__(256) void gcn_relu_kernel(float* __restrict__ out, int n4)
{
    int idx = blockIdx.x * blockDim.x + threadIdx.x;
    if (idx >= n4) return;
    float4* p = reinterpret_cast<float4*>(out) + idx;
    float4 v = *p;
    v.x = fmaxf(v.x, 0.f);
    v.y = fmaxf(v.y, 0.f);
    v.z = fmaxf(v.z, 0.f);
    v.w = fmaxf(v.w, 0.f);
    *p = v;
}

// ---------------------------------------------------------------------------
extern "C" void kernel_launch(void* const* d_in, const int* in_sizes, int n_in,
                              void* d_out, int out_size, void* d_ws, size_t ws_size,
                              hipStream_t stream)
{
    const float* x    = (const float*)d_in[0];
    const float* w    = (const float*)d_in[1];
    const float* vals = (const float*)d_in[2];
    const int*   rows = (const int*)d_in[3];
    const int*   cols = (const int*)d_in[4];
    float* out = (float*)d_out;

    const int n_nodes = in_sizes[0] / IN_F;     // 50000
    const int n_edges = in_sizes[2];            // 800000

    // workspace layout
    char* p = (char*)d_ws;
    float* support = (float*)p;  p += (size_t)n_nodes * OUT_F * sizeof(float);
    int*   offsets = (int*)p;    p += (size_t)(n_nodes + 1) * sizeof(int);
    int*   deg     = (int*)p;    p += (size_t)n_nodes * sizeof(int);
    int*   cnt     = (int*)p;    p += (size_t)n_nodes * sizeof(int);
    int*   csr_col = (int*)p;    p += (size_t)n_edges * sizeof(int);
    float* csr_val = (float*)p;  p += (size_t)n_edges * sizeof(float);
    size_t needed = (size_t)(p - (char*)d_ws);

    // Stage 1: GEMM (both paths need it)
    int gemm_blocks = (n_nodes + BM - 1) / BM;
    gcn_gemm_kernel<<<gemm_blocks, 256, 0, stream>>>(x, w, support, n_nodes);

    const int eb = (n_edges + 255) / 256;

    if (ws_size >= needed) {
        // Stage 2: CSR build
        hipMemsetAsync(deg, 0, (size_t)n_nodes * sizeof(int), stream);
        hipMemsetAsync(cnt, 0, (size_t)n_nodes * sizeof(int), stream);
        gcn_hist_kernel<<<eb, 256, 0, stream>>>(rows, deg, n_edges);
        gcn_scan_kernel<<<1, 1024, 0, stream>>>(deg, offsets, n_nodes);
        gcn_fill_kernel<<<eb, 256, 0, stream>>>(rows, cols, vals, offsets, cnt,
                                                csr_col, csr_val, n_edges);
        // Stage 3: atomic-free accumulate + fused ReLU (overwrites all of out)
        int gb = (n_nodes + 3) / 4;
        gcn_gather_kernel<<<gb, 256, 0, stream>>>(support, offsets, deg,
                                                  csr_col, csr_val, out, n_nodes);
    } else {
        // fallback: proven atomic path
        hipMemsetAsync(d_out, 0, (size_t)out_size * sizeof(float), stream);
        long long total = (long long)n_edges * (OUT_F / 4);
        int sc_blocks = (int)((total + 255) / 256);
        gcn_scatter_kernel<<<sc_blocks, 256, 0, stream>>>(support, vals, rows, cols,
                                                          out, n_edges);
        int n4 = out_size / 4;
        gcn_relu_kernel<<<(n4 + 255) / 256, 256, 0, stream>>>(out, n4);
    }
}

// Round 4
// 207.236 us; speedup vs baseline: 7.2378x; 1.4023x over previous
//
#include <hip/hip_runtime.h>
#include <hip/hip_bf16.h>

// ---------------------------------------------------------------------------
// GCN layer: out = relu(segment_sum(adj_vals * (x@W)[cols], rows))
//   x: [50000,256] f32, W: [256,128] f32, edges: 800000
// Stage 1: register-tiled GEMM support = x @ W  (f32, 64x128 tile, 4x8/thread)
// Stage 2: CSR build: hist -> 3-pass multiblock scan -> fill (atomics convert
//          offsets to end-pointers; no cnt array needed)
// Stage 3: per-node gather-accumulate + ReLU    (atomic-free, fused)
// Fallback (ws too small): atomicAdd scatter path.
// ---------------------------------------------------------------------------

#define IN_F  256
#define OUT_F 128

#define BM 64
#define BN 128
#define BK 32
#define XPAD 68   // padded LDS row for xs_t: float4-aligned, spreads banks

// ---------------------------- Stage 1: GEMM -------------------------------
__global__ __launch_bounds__(256) void gcn_gemm_kernel(
    const float* __restrict__ x, const float* __restrict__ w,
    float* __restrict__ support, int n_nodes)
{
    __shared__ float xs_t[BK][XPAD];   // transposed x tile: [kk][row]
    __shared__ float ws_[BK][BN];      // w tile: 16 KB

    const int tid  = threadIdx.x;
    const int tx   = tid & 15;         // col group: 8 cols each
    const int ty   = tid >> 4;         // row group: 4 rows each
    const int row0 = blockIdx.x * BM;

    float acc[4][8];
#pragma unroll
    for (int i = 0; i < 4; ++i)
#pragma unroll
        for (int j = 0; j < 8; ++j) acc[i][j] = 0.f;

    for (int k0 = 0; k0 < IN_F; k0 += BK) {
#pragma unroll
        for (int i = 0; i < 2; ++i) {
            int t  = tid + i * 256;          // 0..511
            int r  = t >> 3;                 // 0..63
            int kk = (t & 7) << 2;           // 0,4,..,28
            int row = row0 + r;
            float4 v = make_float4(0.f, 0.f, 0.f, 0.f);
            if (row < n_nodes)
                v = *reinterpret_cast<const float4*>(&x[(size_t)row * IN_F + k0 + kk]);
            xs_t[kk + 0][r] = v.x;
            xs_t[kk + 1][r] = v.y;
            xs_t[kk + 2][r] = v.z;
            xs_t[kk + 3][r] = v.w;
        }
#pragma unroll
        for (int i = 0; i < 4; ++i) {
            int fi = tid + i * 256;          // float4 index 0..1023
            int kk = fi >> 5;
            int cc = (fi & 31) << 2;
            *reinterpret_cast<float4*>(&ws_[kk][cc]) =
                *reinterpret_cast<const float4*>(&w[(size_t)(k0 + kk) * OUT_F + cc]);
        }
        __syncthreads();

#pragma unroll
        for (int kk = 0; kk < BK; ++kk) {
            float4 a  = *reinterpret_cast<const float4*>(&xs_t[kk][ty * 4]);
            float4 b0 = *reinterpret_cast<const float4*>(&ws_[kk][tx * 8]);
            float4 b1 = *reinterpret_cast<const float4*>(&ws_[kk][tx * 8 + 4]);
            const float av[4] = {a.x, a.y, a.z, a.w};
            const float bv[8] = {b0.x, b0.y, b0.z, b0.w, b1.x, b1.y, b1.z, b1.w};
#pragma unroll
            for (int i = 0; i < 4; ++i)
#pragma unroll
                for (int j = 0; j < 8; ++j)
                    acc[i][j] += av[i] * bv[j];
        }
        __syncthreads();
    }

#pragma unroll
    for (int i = 0; i < 4; ++i) {
        int row = row0 + ty * 4 + i;
        if (row < n_nodes) {
            float4 o0 = make_float4(acc[i][0], acc[i][1], acc[i][2], acc[i][3]);
            float4 o1 = make_float4(acc[i][4], acc[i][5], acc[i][6], acc[i][7]);
            *reinterpret_cast<float4*>(&support[(size_t)row * OUT_F + tx * 8])     = o0;
            *reinterpret_cast<float4*>(&support[(size_t)row * OUT_F + tx * 8 + 4]) = o1;
        }
    }
}

// ------------------------- Stage 2: CSR build ------------------------------
__global__ __launch_bounds__(256) void gcn_hist_kernel(
    const int* __restrict__ rows, int* __restrict__ deg, int n_edges)
{
    int e = blockIdx.x * blockDim.x + threadIdx.x;
    if (e < n_edges) atomicAdd(&deg[rows[e]], 1);
}

// --- multi-block exclusive scan: pass 1 (block-local scan + block sums) ----
// each block: 256 threads x 4 values = 1024 elements
__global__ __launch_bounds__(256) void gcn_scan1_kernel(
    const int* __restrict__ deg, int* __restrict__ offsets,
    int* __restrict__ block_sums, int n)
{
    __shared__ int part[256];
    const int tid  = threadIdx.x;
    const int base = blockIdx.x * 1024 + tid * 4;

    int4 v = make_int4(0, 0, 0, 0);
    if (base + 3 < n) {
        v = *reinterpret_cast<const int4*>(&deg[base]);
    } else {
        if (base + 0 < n) v.x = deg[base + 0];
        if (base + 1 < n) v.y = deg[base + 1];
        if (base + 2 < n) v.z = deg[base + 2];
        if (base + 3 < n) v.w = deg[base + 3];
    }
    int s = v.x + v.y + v.z + v.w;
    part[tid] = s;
    __syncthreads();
    for (int d = 1; d < 256; d <<= 1) {
        int t = (tid >= d) ? part[tid - d] : 0;
        __syncthreads();
        part[tid] += t;
        __syncthreads();
    }
    int ex = part[tid] - s;   // exclusive prefix within block
    int4 o;
    o.x = ex;
    o.y = o.x + v.x;
    o.z = o.y + v.y;
    o.w = o.z + v.z;
    if (base + 3 < n) {
        *reinterpret_cast<int4*>(&offsets[base]) = o;
    } else {
        if (base + 0 < n) offsets[base + 0] = o.x;
        if (base + 1 < n) offsets[base + 1] = o.y;
        if (base + 2 < n) offsets[base + 2] = o.z;
        if (base + 3 < n) offsets[base + 3] = o.w;
    }
    if (tid == 255) block_sums[blockIdx.x] = part[255];
}

// --- pass 2: exclusive scan of block sums (nb <= 256), in place ------------
__global__ __launch_bounds__(256) void gcn_scan2_kernel(
    int* __restrict__ block_sums, int nb)
{
    __shared__ int part[256];
    const int tid = threadIdx.x;
    int s = (tid < nb) ? block_sums[tid] : 0;
    part[tid] = s;
    __syncthreads();
    for (int d = 1; d < 256; d <<= 1) {
        int t = (tid >= d) ? part[tid - d] : 0;
        __syncthreads();
        part[tid] += t;
        __syncthreads();
    }
    if (tid < nb) block_sums[tid] = part[tid] - s;   // exclusive base
}

// --- pass 3: add block base in place ---------------------------------------
__global__ __launch_bounds__(256) void gcn_scan3_kernel(
    int* __restrict__ offsets, const int* __restrict__ block_sums, int n)
{
    const int base = blockIdx.x * 1024 + threadIdx.x * 4;
    const int add  = block_sums[blockIdx.x];
    if (base + 3 < n) {
        int4 v = *reinterpret_cast<const int4*>(&offsets[base]);
        v.x += add; v.y += add; v.z += add; v.w += add;
        *reinterpret_cast<int4*>(&offsets[base]) = v;
    } else {
        if (base + 0 < n) offsets[base + 0] += add;
        if (base + 1 < n) offsets[base + 1] += add;
        if (base + 2 < n) offsets[base + 2] += add;
        if (base + 3 < n) offsets[base + 3] += add;
    }
}

// --- fill: atomically bump offsets (converts them to end-pointers) ---------
__global__ __launch_bounds__(256) void gcn_fill_kernel(
    const int* __restrict__ rows, const int* __restrict__ cols,
    const float* __restrict__ vals, int* __restrict__ offsets,
    int* __restrict__ csr_col, float* __restrict__ csr_val, int n_edges)
{
    int e = blockIdx.x * blockDim.x + threadIdx.x;
    if (e >= n_edges) return;
    int r = rows[e];
    int pos = atomicAdd(&offsets[r], 1);
    csr_col[pos] = cols[e];
    csr_val[pos] = vals[e];
}

// ---------------- Stage 3: per-node accumulate + ReLU ----------------------
// after fill, offsets[r] is the END pointer of row r; start = offsets[r-1]
// one wave per node; lane l owns features {2l, 2l+1}
__global__ __launch_bounds__(256) void gcn_gather_kernel(
    const float* __restrict__ support, const int* __restrict__ offsets,
    const int* __restrict__ csr_col, const float* __restrict__ csr_val,
    float* __restrict__ out, int n_nodes)
{
    const int node = blockIdx.x * 4 + (threadIdx.x >> 6);
    const int lane = threadIdx.x & 63;
    if (node >= n_nodes) return;

    const int end   = offsets[node];
    const int start = (node == 0) ? 0 : offsets[node - 1];
    const int d     = end - start;
    const int off   = start;

    float2 acc = make_float2(0.f, 0.f);
    int j = 0;
    for (; j + 3 < d; j += 4) {
        int   c0 = csr_col[off + j];
        int   c1 = csr_col[off + j + 1];
        int   c2 = csr_col[off + j + 2];
        int   c3 = csr_col[off + j + 3];
        float v0 = csr_val[off + j];
        float v1 = csr_val[off + j + 1];
        float v2 = csr_val[off + j + 2];
        float v3 = csr_val[off + j + 3];
        float2 s0 = *reinterpret_cast<const float2*>(&support[(size_t)c0 * OUT_F + lane * 2]);
        float2 s1 = *reinterpret_cast<const float2*>(&support[(size_t)c1 * OUT_F + lane * 2]);
        float2 s2 = *reinterpret_cast<const float2*>(&support[(size_t)c2 * OUT_F + lane * 2]);
        float2 s3 = *reinterpret_cast<const float2*>(&support[(size_t)c3 * OUT_F + lane * 2]);
        acc.x += v0 * s0.x + v1 * s1.x + v2 * s2.x + v3 * s3.x;
        acc.y += v0 * s0.y + v1 * s1.y + v2 * s2.y + v3 * s3.y;
    }
    for (; j < d; ++j) {
        int   c0 = csr_col[off + j];
        float v0 = csr_val[off + j];
        float2 s0 = *reinterpret_cast<const float2*>(&support[(size_t)c0 * OUT_F + lane * 2]);
        acc.x += v0 * s0.x;
        acc.y += v0 * s0.y;
    }

    float2 o;
    o.x = fmaxf(acc.x, 0.f);
    o.y = fmaxf(acc.y, 0.f);
    *reinterpret_cast<float2*>(&out[(size_t)node * OUT_F + lane * 2]) = o;
}

// ------------------------- Fallback (atomic) -------------------------------
__global__ __launch_bounds__(256) void gcn_scatter_kernel(
    const float* __restrict__ support, const float* __restrict__ vals,
    const int* __restrict__ rows, const int* __restrict__ cols,
    float* __restrict__ out, int n_edges)
{
    long long idx   = (long long)blockIdx.x * blockDim.x + threadIdx.x;
    long long total = (long long)n_edges * (OUT_F / 4);
    if (idx >= total) return;

    int e  = (int)(idx >> 5);
    int f4 = (int)(idx & 31);
    int r  = rows[e];
    int c  = cols[e];
    float v = vals[e];

    float4 s = *reinterpret_cast<const float4*>(&support[(size_t)c * OUT_F + f4 * 4]);
    float* o = &out[(size_t)r * OUT_F + f4 * 4];
    atomicAdd(o + 0, v * s.x);
    atomicAdd(o + 1, v * s.y);
    atomicAdd(o + 2, v * s.z);
    atomicAdd(o + 3, v * s.w);
}

__global__ __launch_bounds__(256) void gcn_relu_kernel(float* __restrict__ out, int n4)
{
    int idx = blockIdx.x * blockDim.x + threadIdx.x;
    if (idx >= n4) return;
    float4* p = reinterpret_cast<float4*>(out) + idx;
    float4 v = *p;
    v.x = fmaxf(v.x, 0.f);
    v.y = fmaxf(v.y, 0.f);
    v.z = fmaxf(v.z, 0.f);
    v.w = fmaxf(v.w, 0.f);
    *p = v;
}

// ---------------------------------------------------------------------------
static inline char* align16(char* p) {
    return (char*)(((uintptr_t)p + 15) & ~(uintptr_t)15);
}

extern "C" void kernel_launch(void* const* d_in, const int* in_sizes, int n_in,
                              void* d_out, int out_size, void* d_ws, size_t ws_size,
                              hipStream_t stream)
{
    const float* x    = (const float*)d_in[0];
    const float* w    = (const float*)d_in[1];
    const float* vals = (const float*)d_in[2];
    const int*   rows = (const int*)d_in[3];
    const int*   cols = (const int*)d_in[4];
    float* out = (float*)d_out;

    const int n_nodes = in_sizes[0] / IN_F;     // 50000
    const int n_edges = in_sizes[2];            // 800000

    const int scan_blocks = (n_nodes + 1023) / 1024;   // 49 for n=50000

    // workspace layout (16B-aligned slots)
    char* p = (char*)d_ws;
    float* support = (float*)p;  p = align16(p + (size_t)n_nodes * OUT_F * sizeof(float));
    int*   offsets = (int*)p;    p = align16(p + (size_t)n_nodes * sizeof(int));
    int*   deg     = (int*)p;    p = align16(p + (size_t)n_nodes * sizeof(int));
    int*   bsums   = (int*)p;    p = align16(p + (size_t)256 * sizeof(int));
    int*   csr_col = (int*)p;    p = align16(p + (size_t)n_edges * sizeof(int));
    float* csr_val = (float*)p;  p = align16(p + (size_t)n_edges * sizeof(float));
    size_t needed = (size_t)(p - (char*)d_ws);

    // Stage 1: GEMM (both paths need it)
    int gemm_blocks = (n_nodes + BM - 1) / BM;
    gcn_gemm_kernel<<<gemm_blocks, 256, 0, stream>>>(x, w, support, n_nodes);

    const int eb = (n_edges + 255) / 256;

    if (ws_size >= needed && scan_blocks <= 256) {
        // Stage 2: CSR build
        hipMemsetAsync(deg, 0, (size_t)n_nodes * sizeof(int), stream);
        gcn_hist_kernel<<<eb, 256, 0, stream>>>(rows, deg, n_edges);
        gcn_scan1_kernel<<<scan_blocks, 256, 0, stream>>>(deg, offsets, bsums, n_nodes);
        gcn_scan2_kernel<<<1, 256, 0, stream>>>(bsums, scan_blocks);
        gcn_scan3_kernel<<<scan_blocks, 256, 0, stream>>>(offsets, bsums, n_nodes);
        gcn_fill_kernel<<<eb, 256, 0, stream>>>(rows, cols, vals, offsets,
                                                csr_col, csr_val, n_edges);
        // Stage 3: atomic-free accumulate + fused ReLU (overwrites all of out)
        int gb = (n_nodes + 3) / 4;
        gcn_gather_kernel<<<gb, 256, 0, stream>>>(support, offsets,
                                                  csr_col, csr_val, out, n_nodes);
    } else {
        // fallback: proven atomic path
        hipMemsetAsync(d_out, 0, (size_t)out_size * sizeof(float), stream);
        long long total = (long long)n_edges * (OUT_F / 4);
        int sc_blocks = (int)((total + 255) / 256);
        gcn_scatter_kernel<<<sc_blocks, 256, 0, stream>>>(support, vals, rows, cols,
                                                          out, n_edges);
        int n4 = out_size / 4;
        gcn_relu_kernel<<<(n4 + 255) / 256, 256, 0, stream>>>(out, n4);
    }
}

// Round 5
// 206.485 us; speedup vs baseline: 7.2641x; 1.0036x over previous
//
#include <hip/hip_runtime.h>
#include <hip/hip_bf16.h>

// ---------------------------------------------------------------------------
// GCN layer: out = relu(segment_sum(adj_vals * (x@W)[cols], rows))
//   x: [50000,256] f32, W: [256,128] f32, edges: 800000
// Stage 1: register-tiled GEMM support = x @ W
//          64x128 tile, per-thread 8x4, conflict-free LDS read patterns:
//          W reads contiguous-b128 across wave, x reads are broadcasts.
// Stage 2: CSR build: hist -> 3-pass multiblock scan -> fill (atomics convert
//          offsets to end-pointers)
// Stage 3: per-node gather-accumulate + ReLU    (atomic-free, fused)
// Fallback (ws too small): atomicAdd scatter path.
// ---------------------------------------------------------------------------

#define IN_F  256
#define OUT_F 128

#define BM 64
#define BN 128
#define BK 32
#define XPAD 68   // 68*4B per row: keeps float4 alignment of xs_t[kk]

// ---------------------------- Stage 1: GEMM -------------------------------
__global__ __launch_bounds__(256) void gcn_gemm_kernel(
    const float* __restrict__ x, const float* __restrict__ w,
    float* __restrict__ support, int n_nodes)
{
    __shared__ float xs_t[BK][XPAD];   // transposed x tile: [kk][row], 8.7 KB
    __shared__ float ws_[BK][BN];      // w tile: 16 KB

    const int tid  = threadIdx.x;
    const int cg   = tid & 31;         // float4 col chunk: cols cg*4..cg*4+3
    const int rg   = tid >> 5;         // row group 0..7: rows rg*4.. and rg*4+32..
    const int row0 = blockIdx.x * BM;

    float acc[8][4];
#pragma unroll
    for (int i = 0; i < 8; ++i)
#pragma unroll
        for (int j = 0; j < 4; ++j) acc[i][j] = 0.f;

    for (int k0 = 0; k0 < IN_F; k0 += BK) {
        // x tile: 64 rows x 32 k, 2 float4/thread, stored transposed
#pragma unroll
        for (int i = 0; i < 2; ++i) {
            int t   = tid + i * 256;         // 0..511
            int r   = t >> 3;                // 0..63
            int kk  = (t & 7) << 2;          // 0,4,..,28
            int row = row0 + r;
            float4 v = make_float4(0.f, 0.f, 0.f, 0.f);
            if (row < n_nodes)
                v = *reinterpret_cast<const float4*>(&x[(size_t)row * IN_F + k0 + kk]);
            xs_t[kk + 0][r] = v.x;
            xs_t[kk + 1][r] = v.y;
            xs_t[kk + 2][r] = v.z;
            xs_t[kk + 3][r] = v.w;
        }
        // w tile: 32 k x 128 cols, 4 float4/thread, contiguous stores
#pragma unroll
        for (int i = 0; i < 4; ++i) {
            int fi = tid + i * 256;          // float4 index 0..1023
            int kk = fi >> 5;
            int cc = (fi & 31) << 2;
            *reinterpret_cast<float4*>(&ws_[kk][cc]) =
                *reinterpret_cast<const float4*>(&w[(size_t)(k0 + kk) * OUT_F + cc]);
        }
        __syncthreads();

#pragma unroll
        for (int kk = 0; kk < BK; ++kk) {
            // broadcast reads (2 addresses per wave each) — conflict-free
            float4 a0 = *reinterpret_cast<const float4*>(&xs_t[kk][rg * 4]);
            float4 a1 = *reinterpret_cast<const float4*>(&xs_t[kk][rg * 4 + 32]);
            // contiguous b128 across wave — measured-fast pattern
            float4 b  = *reinterpret_cast<const float4*>(&ws_[kk][cg * 4]);
            const float av[8] = {a0.x, a0.y, a0.z, a0.w, a1.x, a1.y, a1.z, a1.w};
            const float bv[4] = {b.x, b.y, b.z, b.w};
#pragma unroll
            for (int i = 0; i < 8; ++i)
#pragma unroll
                for (int j = 0; j < 4; ++j)
                    acc[i][j] += av[i] * bv[j];
        }
        __syncthreads();
    }

#pragma unroll
    for (int i = 0; i < 8; ++i) {
        int row = row0 + rg * 4 + (i & 3) + (i >> 2) * 32;
        if (row < n_nodes) {
            float4 o = make_float4(acc[i][0], acc[i][1], acc[i][2], acc[i][3]);
            *reinterpret_cast<float4*>(&support[(size_t)row * OUT_F + cg * 4]) = o;
        }
    }
}

// ------------------------- Stage 2: CSR build ------------------------------
__global__ __launch_bounds__(256) void gcn_hist_kernel(
    const int* __restrict__ rows, int* __restrict__ deg, int n_edges)
{
    int e = blockIdx.x * blockDim.x + threadIdx.x;
    if (e < n_edges) atomicAdd(&deg[rows[e]], 1);
}

// --- multi-block exclusive scan: pass 1 (block-local scan + block sums) ----
__global__ __launch_bounds__(256) void gcn_scan1_kernel(
    const int* __restrict__ deg, int* __restrict__ offsets,
    int* __restrict__ block_sums, int n)
{
    __shared__ int part[256];
    const int tid  = threadIdx.x;
    const int base = blockIdx.x * 1024 + tid * 4;

    int4 v = make_int4(0, 0, 0, 0);
    if (base + 3 < n) {
        v = *reinterpret_cast<const int4*>(&deg[base]);
    } else {
        if (base + 0 < n) v.x = deg[base + 0];
        if (base + 1 < n) v.y = deg[base + 1];
        if (base + 2 < n) v.z = deg[base + 2];
        if (base + 3 < n) v.w = deg[base + 3];
    }
    int s = v.x + v.y + v.z + v.w;
    part[tid] = s;
    __syncthreads();
    for (int d = 1; d < 256; d <<= 1) {
        int t = (tid >= d) ? part[tid - d] : 0;
        __syncthreads();
        part[tid] += t;
        __syncthreads();
    }
    int ex = part[tid] - s;
    int4 o;
    o.x = ex;
    o.y = o.x + v.x;
    o.z = o.y + v.y;
    o.w = o.z + v.z;
    if (base + 3 < n) {
        *reinterpret_cast<int4*>(&offsets[base]) = o;
    } else {
        if (base + 0 < n) offsets[base + 0] = o.x;
        if (base + 1 < n) offsets[base + 1] = o.y;
        if (base + 2 < n) offsets[base + 2] = o.z;
        if (base + 3 < n) offsets[base + 3] = o.w;
    }
    if (tid == 255) block_sums[blockIdx.x] = part[255];
}

__global__ __launch_bounds__(256) void gcn_scan2_kernel(
    int* __restrict__ block_sums, int nb)
{
    __shared__ int part[256];
    const int tid = threadIdx.x;
    int s = (tid < nb) ? block_sums[tid] : 0;
    part[tid] = s;
    __syncthreads();
    for (int d = 1; d < 256; d <<= 1) {
        int t = (tid >= d) ? part[tid - d] : 0;
        __syncthreads();
        part[tid] += t;
        __syncthreads();
    }
    if (tid < nb) block_sums[tid] = part[tid] - s;
}

__global__ __launch_bounds__(256) void gcn_scan3_kernel(
    int* __restrict__ offsets, const int* __restrict__ block_sums, int n)
{
    const int base = blockIdx.x * 1024 + threadIdx.x * 4;
    const int add  = block_sums[blockIdx.x];
    if (base + 3 < n) {
        int4 v = *reinterpret_cast<const int4*>(&offsets[base]);
        v.x += add; v.y += add; v.z += add; v.w += add;
        *reinterpret_cast<int4*>(&offsets[base]) = v;
    } else {
        if (base + 0 < n) offsets[base + 0] += add;
        if (base + 1 < n) offsets[base + 1] += add;
        if (base + 2 < n) offsets[base + 2] += add;
        if (base + 3 < n) offsets[base + 3] += add;
    }
}

// --- fill: atomically bump offsets (converts them to end-pointers) ---------
__global__ __launch_bounds__(256) void gcn_fill_kernel(
    const int* __restrict__ rows, const int* __restrict__ cols,
    const float* __restrict__ vals, int* __restrict__ offsets,
    int* __restrict__ csr_col, float* __restrict__ csr_val, int n_edges)
{
    int e = blockIdx.x * blockDim.x + threadIdx.x;
    if (e >= n_edges) return;
    int r = rows[e];
    int pos = atomicAdd(&offsets[r], 1);
    csr_col[pos] = cols[e];
    csr_val[pos] = vals[e];
}

// ---------------- Stage 3: per-node accumulate + ReLU ----------------------
// after fill, offsets[r] is the END pointer of row r; start = offsets[r-1]
__global__ __launch_bounds__(256) void gcn_gather_kernel(
    const float* __restrict__ support, const int* __restrict__ offsets,
    const int* __restrict__ csr_col, const float* __restrict__ csr_val,
    float* __restrict__ out, int n_nodes)
{
    const int node = blockIdx.x * 4 + (threadIdx.x >> 6);
    const int lane = threadIdx.x & 63;
    if (node >= n_nodes) return;

    const int end   = offsets[node];
    const int start = (node == 0) ? 0 : offsets[node - 1];
    const int d     = end - start;
    const int off   = start;

    float2 acc = make_float2(0.f, 0.f);
    int j = 0;
    for (; j + 3 < d; j += 4) {
        int   c0 = csr_col[off + j];
        int   c1 = csr_col[off + j + 1];
        int   c2 = csr_col[off + j + 2];
        int   c3 = csr_col[off + j + 3];
        float v0 = csr_val[off + j];
        float v1 = csr_val[off + j + 1];
        float v2 = csr_val[off + j + 2];
        float v3 = csr_val[off + j + 3];
        float2 s0 = *reinterpret_cast<const float2*>(&support[(size_t)c0 * OUT_F + lane * 2]);
        float2 s1 = *reinterpret_cast<const float2*>(&support[(size_t)c1 * OUT_F + lane * 2]);
        float2 s2 = *reinterpret_cast<const float2*>(&support[(size_t)c2 * OUT_F + lane * 2]);
        float2 s3 = *reinterpret_cast<const float2*>(&support[(size_t)c3 * OUT_F + lane * 2]);
        acc.x += v0 * s0.x + v1 * s1.x + v2 * s2.x + v3 * s3.x;
        acc.y += v0 * s0.y + v1 * s1.y + v2 * s2.y + v3 * s3.y;
    }
    for (; j < d; ++j) {
        int   c0 = csr_col[off + j];
        float v0 = csr_val[off + j];
        float2 s0 = *reinterpret_cast<const float2*>(&support[(size_t)c0 * OUT_F + lane * 2]);
        acc.x += v0 * s0.x;
        acc.y += v0 * s0.y;
    }

    float2 o;
    o.x = fmaxf(acc.x, 0.f);
    o.y = fmaxf(acc.y, 0.f);
    *reinterpret_cast<float2*>(&out[(size_t)node * OUT_F + lane * 2]) = o;
}

// ------------------------- Fallback (atomic) -------------------------------
__global__ __launch_bounds__(256) void gcn_scatter_kernel(
    const float* __restrict__ support, const float* __restrict__ vals,
    const int* __restrict__ rows, const int* __restrict__ cols,
    float* __restrict__ out, int n_edges)
{
    long long idx   = (long long)blockIdx.x * blockDim.x + threadIdx.x;
    long long total = (long long)n_edges * (OUT_F / 4);
    if (idx >= total) return;

    int e  = (int)(idx >> 5);
    int f4 = (int)(idx & 31);
    int r  = rows[e];
    int c  = cols[e];
    float v = vals[e];

    float4 s = *reinterpret_cast<const float4*>(&support[(size_t)c * OUT_F + f4 * 4]);
    float* o = &out[(size_t)r * OUT_F + f4 * 4];
    atomicAdd(o + 0, v * s.x);
    atomicAdd(o + 1, v * s.y);
    atomicAdd(o + 2, v * s.z);
    atomicAdd(o + 3, v * s.w);
}

__global__ __launch_bounds__(256) void gcn_relu_kernel(float* __restrict__ out, int n4)
{
    int idx = blockIdx.x * blockDim.x + threadIdx.x;
    if (idx >= n4) return;
    float4* p = reinterpret_cast<float4*>(out) + idx;
    float4 v = *p;
    v.x = fmaxf(v.x, 0.f);
    v.y = fmaxf(v.y, 0.f);
    v.z = fmaxf(v.z, 0.f);
    v.w = fmaxf(v.w, 0.f);
    *p = v;
}

// ---------------------------------------------------------------------------
static inline char* align16(char* p) {
    return (char*)(((uintptr_t)p + 15) & ~(uintptr_t)15);
}

extern "C" void kernel_launch(void* const* d_in, const int* in_sizes, int n_in,
                              void* d_out, int out_size, void* d_ws, size_t ws_size,
                              hipStream_t stream)
{
    const float* x    = (const float*)d_in[0];
    const float* w    = (const float*)d_in[1];
    const float* vals = (const float*)d_in[2];
    const int*   rows = (const int*)d_in[3];
    const int*   cols = (const int*)d_in[4];
    float* out = (float*)d_out;

    const int n_nodes = in_sizes[0] / IN_F;     // 50000
    const int n_edges = in_sizes[2];            // 800000

    const int scan_blocks = (n_nodes + 1023) / 1024;   // 49 for n=50000

    // workspace layout (16B-aligned slots)
    char* p = (char*)d_ws;
    float* support = (float*)p;  p = align16(p + (size_t)n_nodes * OUT_F * sizeof(float));
    int*   offsets = (int*)p;    p = align16(p + (size_t)n_nodes * sizeof(int));
    int*   deg     = (int*)p;    p = align16(p + (size_t)n_nodes * sizeof(int));
    int*   bsums   = (int*)p;    p = align16(p + (size_t)256 * sizeof(int));
    int*   csr_col = (int*)p;    p = align16(p + (size_t)n_edges * sizeof(int));
    float* csr_val = (float*)p;  p = align16(p + (size_t)n_edges * sizeof(float));
    size_t needed = (size_t)(p - (char*)d_ws);

    // Stage 1: GEMM (both paths need it)
    int gemm_blocks = (n_nodes + BM - 1) / BM;
    gcn_gemm_kernel<<<gemm_blocks, 256, 0, stream>>>(x, w, support, n_nodes);

    const int eb = (n_edges + 255) / 256;

    if (ws_size >= needed && scan_blocks <= 256) {
        // Stage 2: CSR build
        hipMemsetAsync(deg, 0, (size_t)n_nodes * sizeof(int), stream);
        gcn_hist_kernel<<<eb, 256, 0, stream>>>(rows, deg, n_edges);
        gcn_scan1_kernel<<<scan_blocks, 256, 0, stream>>>(deg, offsets, bsums, n_nodes);
        gcn_scan2_kernel<<<1, 256, 0, stream>>>(bsums, scan_blocks);
        gcn_scan3_kernel<<<scan_blocks, 256, 0, stream>>>(offsets, bsums, n_nodes);
        gcn_fill_kernel<<<eb, 256, 0, stream>>>(rows, cols, vals, offsets,
                                                csr_col, csr_val, n_edges);
        // Stage 3: atomic-free accumulate + fused ReLU
        int gb = (n_nodes + 3) / 4;
        gcn_gather_kernel<<<gb, 256, 0, stream>>>(support, offsets,
                                                  csr_col, csr_val, out, n_nodes);
    } else {
        // fallback: proven atomic path
        hipMemsetAsync(d_out, 0, (size_t)out_size * sizeof(float), stream);
        long long total = (long long)n_edges * (OUT_F / 4);
        int sc_blocks = (int)((total + 255) / 256);
        gcn_scatter_kernel<<<sc_blocks, 256, 0, stream>>>(support, vals, rows, cols,
                                                          out, n_edges);
        int n4 = out_size / 4;
        gcn_relu_kernel<<<(n4 + 255) / 256, 256, 0, stream>>>(out, n4);
    }
}